// Round 9
// baseline (248.214 us; speedup 1.0000x reference)
//
#include <hip/hip_runtime.h>

// logeig(M) for SPD M = A A^T/64 + I; spectrum in [1,~6.6]; w = (M-4.7I)/3.8.
// Deg-11 poly of log via PS s=2 Horner: T=q5; T = T*W2 + q_s (s=4..0).
// One wave == one matrix, zero barriers after P0, state in registers.
//
// R9: OCCUPANCY push to 3 waves/SIMD (R8 showed latency-bound: MFMA work
// -40% gave -4% time; both pipes <30% busy). (1) In-place Horner: pre-split
// all 8 T-frags (32 regs), overwrite T with q_s, MFMA into T -- no d array,
// -64 regs; __launch_bounds__(64,3). (2) f16 w-plane [64][68] (8.5 KB LDS,
// was 16 KB f32): q_s needs only f16-precision w; +4 pad makes col-reads
// 2-way bank-aliased (free). (3) P1 keeps near-exact W2: hi-frag from f16
// plane, lo-frag = rem(w_exact - hi) with w recomputed from one-time global
// re-read of M (L2-hot). (4) diag one-hot as packed-f16 dvp[8] consumed by
// v_fma_mix_f32. Single RNE-f16 T x RNE-f16 W2 in Horner (R8-validated).

typedef __attribute__((ext_vector_type(8)))  __fp16       hfrag;   // 4 VGPR
typedef __attribute__((ext_vector_type(16))) float        facc;    // 16 VGPR
typedef __attribute__((ext_vector_type(4)))  unsigned int uint4v;
typedef __attribute__((ext_vector_type(2)))  unsigned int uint2v;

#define MFMA(a, b, c) __builtin_amdgcn_mfma_f32_32x32x16_f16((a), (b), (c), 0, 0, 0)

static __device__ __forceinline__ void plswap(unsigned& a, unsigned& b) {
    auto r = __builtin_amdgcn_permlane32_swap(a, b, false, false);
    a = (unsigned)r[0];  // {a lanes 0-31, b lanes 0-31}
    b = (unsigned)r[1];  // {a lanes 32-63, b lanes 32-63}
}
static __device__ __forceinline__ unsigned pk2rn(float x, float y) {  // RNE
    _Float16 hx = (_Float16)x, hy = (_Float16)y;
    unsigned short ux = __builtin_bit_cast(unsigned short, hx);
    unsigned short uy = __builtin_bit_cast(unsigned short, hy);
    return (unsigned)ux | ((unsigned)uy << 16);
}
// f16 pack of (x - f32(hw.lo), y - f32(hw.hi)) via mixed-precision FMA.
static __device__ __forceinline__ unsigned rem_pk(unsigned hw, float x, float y,
                                                  float mone) {
    unsigned r = 0;
    asm("v_fma_mixlo_f16 %0, %1, %2, %3 op_sel:[0,0,0] op_sel_hi:[1,0,0]"
        : "+v"(r) : "v"(hw), "v"(mone), "v"(x));
    asm("v_fma_mixhi_f16 %0, %1, %2, %3 op_sel:[1,0,0] op_sel_hi:[1,0,0]"
        : "+v"(r) : "v"(hw), "v"(mone), "v"(y));
    return r;
}
// f32 = f16(pair.half) * s + acc   (one VOP3P instruction)
template <int HI>
static __device__ __forceinline__ float fmix(unsigned pair, float s, float acc) {
    float r;
    if (HI)
        asm("v_fma_mix_f32 %0, %1, %2, %3 op_sel:[1,0,0] op_sel_hi:[1,0,0]"
            : "=v"(r) : "v"(pair), "v"(s), "v"(acc));
    else
        asm("v_fma_mix_f32 %0, %1, %2, %3 op_sel:[0,0,0] op_sel_hi:[1,0,0]"
            : "=v"(r) : "v"(pair), "v"(s), "v"(acc));
    return r;
}

// Single RNE-rounded f16 frag of a C-acc tile half (W2 and Horner T).
static __device__ __forceinline__ hfrag round_frag(const facc& a, int b) {
    unsigned Ph[2][2];
#pragma unroll
    for (int hs = 0; hs < 2; ++hs)
#pragma unroll
        for (int p = 0; p < 2; ++p) {
            int r0 = ((hs + 2 * b) << 2) + (p << 1);
            Ph[hs][p] = pk2rn(a[r0], a[r0 + 1]);
        }
    plswap(Ph[0][0], Ph[1][0]);
    plswap(Ph[0][1], Ph[1][1]);
    uint4v u;
    u[0] = Ph[0][0]; u[1] = Ph[0][1]; u[2] = Ph[1][0]; u[3] = Ph[1][1];
    return __builtin_bit_cast(hfrag, u);
}

// D := kI*I + kw*w at this wave's C-layout positions (f16 plane, fma_mix).
static __device__ __forceinline__ void qs_fill(
    facc (&D)[2][2], const unsigned short* w16, const unsigned (&dvp)[8],
    int ln, int h, float kI, float kw) {
#pragma unroll
    for (int ti = 0; ti < 2; ++ti)
#pragma unroll
        for (int tj = 0; tj < 2; ++tj) {
            int col = (tj << 5) + ln;
#pragma unroll
            for (int qd = 0; qd < 4; ++qd) {
                int qb = (ti << 5) + (qd << 3) + (h << 2);
                uint2v u = *(const uint2v*)(w16 + col * 68 + qb);  // w[qb..qb+3][col]
#pragma unroll
                for (int k = 0; k < 4; ++k) {
                    unsigned wp = (k & 2) ? u[1] : u[0];
                    float b;
                    if (ti == tj) {
                        unsigned dp = dvp[(qd << 1) + (k >> 1)];
                        b = (k & 1) ? fmix<1>(dp, kI, 0.0f) : fmix<0>(dp, kI, 0.0f);
                        b = (k & 1) ? fmix<1>(wp, kw, b) : fmix<0>(wp, kw, b);
                    } else {
                        b = (k & 1) ? fmix<1>(wp, kw, 0.0f) : fmix<0>(wp, kw, 0.0f);
                    }
                    D[ti][tj][(qd << 2) + k] = b;
                }
            }
        }
}

// One in-place Horner step: T := kI*I + kw*w + round16(T)*W2.
static __device__ __forceinline__ void horner_step_ip(
    facc (&T)[2][2], const hfrag (&W2f)[2][4], const unsigned short* w16,
    const unsigned (&dvp)[8], int ln, int h, float kI, float kw) {
    hfrag tf[2][4];  // all A-frags extracted before T is overwritten
#pragma unroll
    for (int kb = 0; kb < 4; ++kb) {
        tf[0][kb] = round_frag(T[kb >> 1][0], kb & 1);
        tf[1][kb] = round_frag(T[kb >> 1][1], kb & 1);
    }
    qs_fill(T, w16, dvp, ln, h, kI, kw);
    __builtin_amdgcn_s_setprio(1);
#pragma unroll
    for (int kb = 0; kb < 4; ++kb)
#pragma unroll
        for (int tj = 0; tj < 2; ++tj) {
            T[0][tj] = MFMA(tf[0][kb], W2f[tj][kb], T[0][tj]);
            T[1][tj] = MFMA(tf[1][kb], W2f[tj][kb], T[1][tj]);
        }
    __builtin_amdgcn_s_setprio(0);
}

__global__ void __launch_bounds__(64, 3)
logeig_mfma_kernel(const float* __restrict__ in, float* __restrict__ out) {
    // monomial coeffs of deg-11 Chebyshev fit of log on [0.9, 8.5] in w
    constexpr float Bc[12] = {1.547606f,  0.808267f,  -0.329629f, 0.182560f,
                              -0.077085f, 0.022485f,  -0.158573f, 0.172463f,
                              0.154589f,  -0.173671f, -0.119491f, 0.110580f};

    // f16 w-plane, rows padded 64->68 (2-way bank aliasing on col reads).
    __shared__ __align__(8) unsigned short w16[64 * 68];  // 8704 B

    const int l  = threadIdx.x;
    const int h  = l >> 5;
    const int ln = l & 31;
    const float mone = -1.0f;

    const size_t mat = blockIdx.x;
    const float* g  = in  + (mat << 12);
    float*       go = out + (mat << 12);

    // one-hot diag selector packed as f16 pairs (reg 2j, 2j+1)
    unsigned dvp[8];
#pragma unroll
    for (int j = 0; j < 8; ++j) {
        int r0 = ((2 * j) & 3) + (((2 * j) >> 2) << 3) + (h << 2);
        int r1 = ((2 * j + 1) & 3) + (((2 * j + 1) >> 2) << 3) + (h << 2);
        dvp[j] = pk2rn(r0 == ln ? 1.0f : 0.0f, r1 == ln ? 1.0f : 0.0f);
    }

    // ---- P0: load M (coalesced float4), w = (M-4.7I)/3.8 -> RNE f16 plane.
#pragma unroll
    for (int rep = 0; rep < 16; ++rep) {
        int f = l + (rep << 6);
        int r = f >> 4, c4 = (f & 15) << 2;
        float4 v = ((const float4*)g)[f];
        float4 wv;
        wv.x = (v.x - ((r == c4 + 0) ? 4.7f : 0.0f)) * (1.0f / 3.8f);
        wv.y = (v.y - ((r == c4 + 1) ? 4.7f : 0.0f)) * (1.0f / 3.8f);
        wv.z = (v.z - ((r == c4 + 2) ? 4.7f : 0.0f)) * (1.0f / 3.8f);
        wv.w = (v.w - ((r == c4 + 3) ? 4.7f : 0.0f)) * (1.0f / 3.8f);
        uint2v st;
        st[0] = pk2rn(wv.x, wv.y);
        st[1] = pk2rn(wv.z, wv.w);
        *(uint2v*)(w16 + r * 68 + c4) = st;
    }
    __syncthreads();  // single-wave block: just orders LDS

    // ---- P1 frags: hi from f16 plane; lo = rem vs exact w (global re-read,
    // L2-hot -- M was fetched microseconds ago by this block).
    hfrag wfh[2][4], wfl[2][4];
#pragma unroll
    for (int t = 0; t < 2; ++t)
#pragma unroll
        for (int kb = 0; kb < 4; ++kb) {
            int row = (t << 5) + ln, q0 = (kb << 4) + (h << 3);
            uint2v a  = *(const uint2v*)(w16 + row * 68 + q0);
            uint2v b2 = *(const uint2v*)(w16 + row * 68 + q0 + 4);
            uint4v uh;
            uh[0] = a[0]; uh[1] = a[1]; uh[2] = b2[0]; uh[3] = b2[1];
            wfh[t][kb] = __builtin_bit_cast(hfrag, uh);
            const float* src = g + (row << 6) + q0;
            float4 v0 = *(const float4*)(src);
            float4 v1 = *(const float4*)(src + 4);
            float e[8] = {v0.x, v0.y, v0.z, v0.w, v1.x, v1.y, v1.z, v1.w};
#pragma unroll
            for (int j = 0; j < 8; ++j) {
                float dia = (q0 + j == row) ? 4.7f : 0.0f;
                e[j] = (e[j] - dia) * (1.0f / 3.8f);
            }
            uint4v ul;
#pragma unroll
            for (int j = 0; j < 4; ++j)
                ul[j] = rem_pk(uh[j], e[2 * j], e[2 * j + 1], mone);
            wfl[t][kb] = __builtin_bit_cast(hfrag, ul);
        }

    // ---- P1: W2 = w*w (hh + hl + lh -> near-exact, exactly symmetric).
    facc c[2][2];
#pragma unroll
    for (int ti = 0; ti < 2; ++ti)
#pragma unroll
        for (int tj = 0; tj < 2; ++tj) c[ti][tj] = (facc)0.0f;
    __builtin_amdgcn_s_setprio(1);
#pragma unroll
    for (int kb = 0; kb < 4; ++kb)
#pragma unroll
        for (int ti = 0; ti < 2; ++ti) {
            hfrag ah = wfh[ti][kb], al = wfl[ti][kb];
#pragma unroll
            for (int tj = 0; tj < 2; ++tj) {
                c[ti][tj] = MFMA(ah, wfh[tj][kb], c[ti][tj]);
                c[ti][tj] = MFMA(ah, wfl[tj][kb], c[ti][tj]);
                c[ti][tj] = MFMA(al, wfh[tj][kb], c[ti][tj]);
            }
        }
    __builtin_amdgcn_s_setprio(0);

    // ---- W2 B-frags: single RNE f16, persistent (32 VGPR).
    hfrag W2f[2][4];
#pragma unroll
    for (int kb = 0; kb < 4; ++kb)
#pragma unroll
        for (int tj = 0; tj < 2; ++tj)
            W2f[tj][kb] = round_frag(c[kb >> 1][tj], kb & 1);

    // ---- T = q5, then Horner s=4..0 fully in place.
    facc T[2][2];
    qs_fill(T, w16, dvp, ln, h, Bc[10], Bc[11]);
    horner_step_ip(T, W2f, w16, dvp, ln, h, Bc[8], Bc[9]);  // s=4
    horner_step_ip(T, W2f, w16, dvp, ln, h, Bc[6], Bc[7]);  // s=3
    horner_step_ip(T, W2f, w16, dvp, ln, h, Bc[4], Bc[5]);  // s=2
    horner_step_ip(T, W2f, w16, dvp, ln, h, Bc[2], Bc[3]);  // s=1
    horner_step_ip(T, W2f, w16, dvp, ln, h, Bc[0], Bc[1]);  // s=0

    // ---- out = T: C-layout straight to global (two 128B segments/instr)
#pragma unroll
    for (int ti = 0; ti < 2; ++ti)
#pragma unroll
        for (int tj = 0; tj < 2; ++tj)
#pragma unroll
            for (int reg = 0; reg < 16; ++reg) {
                int row = (ti << 5) + (reg & 3) + ((reg >> 2) << 3) + (h << 2);
                go[(row << 6) + (tj << 5) + ln] = T[ti][tj][reg];
            }
}

extern "C" void kernel_launch(void* const* d_in, const int* in_sizes, int n_in,
                              void* d_out, int out_size, void* d_ws, size_t ws_size,
                              hipStream_t stream) {
    const float* in = (const float*)d_in[0];
    float* out = (float*)d_out;
    const int batch = in_sizes[0] >> 12;  // 8192 matrices of 64x64
    hipLaunchKernelGGL(logeig_mfma_kernel, dim3(batch), dim3(64), 0,
                       stream, in, out);
}

// Round 10
// 242.572 us; speedup vs baseline: 1.0233x; 1.0233x over previous
//
#include <hip/hip_runtime.h>

// logeig(M) for SPD M = A A^T/64 + I; spectrum in [1,~6.6]; w = (M-4.7I)/3.8.
// Deg-11 poly of log via PS s=2 Horner: T=q5; T = T*W2 + q_s (s=4..0).
// One wave == one matrix, zero barriers after P0, state in registers.
//
// R10 = R9 minus the P1 global re-read (R9: +58MB HBM fetch, L2 did NOT
// retain M across 9 interleaved blocks/CU -> ate the occupancy gain).
// The lo-remainder is now a SECOND f16 LDS plane written in P0 where exact
// f32 w is in registers: lo = rem_pk(hi, w), exact. LDS 2x[64][68] f16 =
// 17.4 KB -> 9 blocks/CU (matches R9's measured occupancy). Keepers from
// R9: padded planes (0 bank conflicts), in-place Horner (-64 regs, VGPR 76),
// fmix q_s, packed-f16 dvp diag, LB(64,3). Horner: single RNE-f16 T x
// RNE-f16 W2 (R8-validated, absmax unchanged at poly floor 2^-8).

typedef __attribute__((ext_vector_type(8)))  __fp16       hfrag;   // 4 VGPR
typedef __attribute__((ext_vector_type(16))) float        facc;    // 16 VGPR
typedef __attribute__((ext_vector_type(4)))  unsigned int uint4v;
typedef __attribute__((ext_vector_type(2)))  unsigned int uint2v;

#define MFMA(a, b, c) __builtin_amdgcn_mfma_f32_32x32x16_f16((a), (b), (c), 0, 0, 0)

static __device__ __forceinline__ void plswap(unsigned& a, unsigned& b) {
    auto r = __builtin_amdgcn_permlane32_swap(a, b, false, false);
    a = (unsigned)r[0];  // {a lanes 0-31, b lanes 0-31}
    b = (unsigned)r[1];  // {a lanes 32-63, b lanes 32-63}
}
static __device__ __forceinline__ unsigned pk2rn(float x, float y) {  // RNE
    _Float16 hx = (_Float16)x, hy = (_Float16)y;
    unsigned short ux = __builtin_bit_cast(unsigned short, hx);
    unsigned short uy = __builtin_bit_cast(unsigned short, hy);
    return (unsigned)ux | ((unsigned)uy << 16);
}
// f16 pack of (x - f32(hw.lo), y - f32(hw.hi)) via mixed-precision FMA.
static __device__ __forceinline__ unsigned rem_pk(unsigned hw, float x, float y,
                                                  float mone) {
    unsigned r = 0;
    asm("v_fma_mixlo_f16 %0, %1, %2, %3 op_sel:[0,0,0] op_sel_hi:[1,0,0]"
        : "+v"(r) : "v"(hw), "v"(mone), "v"(x));
    asm("v_fma_mixhi_f16 %0, %1, %2, %3 op_sel:[1,0,0] op_sel_hi:[1,0,0]"
        : "+v"(r) : "v"(hw), "v"(mone), "v"(y));
    return r;
}
// f32 = f16(pair.half) * s + acc   (one VOP3P instruction)
template <int HI>
static __device__ __forceinline__ float fmix(unsigned pair, float s, float acc) {
    float r;
    if (HI)
        asm("v_fma_mix_f32 %0, %1, %2, %3 op_sel:[1,0,0] op_sel_hi:[1,0,0]"
            : "=v"(r) : "v"(pair), "v"(s), "v"(acc));
    else
        asm("v_fma_mix_f32 %0, %1, %2, %3 op_sel:[0,0,0] op_sel_hi:[1,0,0]"
            : "=v"(r) : "v"(pair), "v"(s), "v"(acc));
    return r;
}

// Single RNE-rounded f16 frag of a C-acc tile half (W2 and Horner T).
static __device__ __forceinline__ hfrag round_frag(const facc& a, int b) {
    unsigned Ph[2][2];
#pragma unroll
    for (int hs = 0; hs < 2; ++hs)
#pragma unroll
        for (int p = 0; p < 2; ++p) {
            int r0 = ((hs + 2 * b) << 2) + (p << 1);
            Ph[hs][p] = pk2rn(a[r0], a[r0 + 1]);
        }
    plswap(Ph[0][0], Ph[1][0]);
    plswap(Ph[0][1], Ph[1][1]);
    uint4v u;
    u[0] = Ph[0][0]; u[1] = Ph[0][1]; u[2] = Ph[1][0]; u[3] = Ph[1][1];
    return __builtin_bit_cast(hfrag, u);
}

// D := kI*I + kw*w at this wave's C-layout positions (f16 hi-plane, fma_mix).
static __device__ __forceinline__ void qs_fill(
    facc (&D)[2][2], const unsigned short* w16, const unsigned (&dvp)[8],
    int ln, int h, float kI, float kw) {
#pragma unroll
    for (int ti = 0; ti < 2; ++ti)
#pragma unroll
        for (int tj = 0; tj < 2; ++tj) {
            int col = (tj << 5) + ln;
#pragma unroll
            for (int qd = 0; qd < 4; ++qd) {
                int qb = (ti << 5) + (qd << 3) + (h << 2);
                uint2v u = *(const uint2v*)(w16 + col * 68 + qb);  // w[qb..qb+3][col]
#pragma unroll
                for (int k = 0; k < 4; ++k) {
                    unsigned wp = (k & 2) ? u[1] : u[0];
                    float b;
                    if (ti == tj) {
                        unsigned dp = dvp[(qd << 1) + (k >> 1)];
                        b = (k & 1) ? fmix<1>(dp, kI, 0.0f) : fmix<0>(dp, kI, 0.0f);
                        b = (k & 1) ? fmix<1>(wp, kw, b) : fmix<0>(wp, kw, b);
                    } else {
                        b = (k & 1) ? fmix<1>(wp, kw, 0.0f) : fmix<0>(wp, kw, 0.0f);
                    }
                    D[ti][tj][(qd << 2) + k] = b;
                }
            }
        }
}

// One in-place Horner step: T := kI*I + kw*w + round16(T)*W2.
static __device__ __forceinline__ void horner_step_ip(
    facc (&T)[2][2], const hfrag (&W2f)[2][4], const unsigned short* w16,
    const unsigned (&dvp)[8], int ln, int h, float kI, float kw) {
    hfrag tf[2][4];  // all A-frags extracted before T is overwritten
#pragma unroll
    for (int kb = 0; kb < 4; ++kb) {
        tf[0][kb] = round_frag(T[kb >> 1][0], kb & 1);
        tf[1][kb] = round_frag(T[kb >> 1][1], kb & 1);
    }
    qs_fill(T, w16, dvp, ln, h, kI, kw);
    __builtin_amdgcn_s_setprio(1);
#pragma unroll
    for (int kb = 0; kb < 4; ++kb)
#pragma unroll
        for (int tj = 0; tj < 2; ++tj) {
            T[0][tj] = MFMA(tf[0][kb], W2f[tj][kb], T[0][tj]);
            T[1][tj] = MFMA(tf[1][kb], W2f[tj][kb], T[1][tj]);
        }
    __builtin_amdgcn_s_setprio(0);
}

__global__ void __launch_bounds__(64, 3)
logeig_mfma_kernel(const float* __restrict__ in, float* __restrict__ out) {
    // monomial coeffs of deg-11 Chebyshev fit of log on [0.9, 8.5] in w
    constexpr float Bc[12] = {1.547606f,  0.808267f,  -0.329629f, 0.182560f,
                              -0.077085f, 0.022485f,  -0.158573f, 0.172463f,
                              0.154589f,  -0.173671f, -0.119491f, 0.110580f};

    // f16 hi/lo w-planes, rows padded 64->68 (conflict-free col reads).
    __shared__ __align__(16) unsigned short w16[2 * 64 * 68];  // 17408 B
    unsigned short* w16h = w16;
    unsigned short* w16l = w16 + 64 * 68;

    const int l  = threadIdx.x;
    const int h  = l >> 5;
    const int ln = l & 31;
    const float mone = -1.0f;

    const size_t mat = blockIdx.x;
    const float* g  = in  + (mat << 12);
    float*       go = out + (mat << 12);

    // one-hot diag selector packed as f16 pairs (reg 2j, 2j+1)
    unsigned dvp[8];
#pragma unroll
    for (int j = 0; j < 8; ++j) {
        int r0 = ((2 * j) & 3) + (((2 * j) >> 2) << 3) + (h << 2);
        int r1 = ((2 * j + 1) & 3) + (((2 * j + 1) >> 2) << 3) + (h << 2);
        dvp[j] = pk2rn(r0 == ln ? 1.0f : 0.0f, r1 == ln ? 1.0f : 0.0f);
    }

    // ---- P0: load M (coalesced float4), w = (M-4.7I)/3.8; hi = RNE f16,
    // lo = exact remainder (w still exact f32 in regs here) -> two planes.
#pragma unroll
    for (int rep = 0; rep < 16; ++rep) {
        int f = l + (rep << 6);
        int r = f >> 4, c4 = (f & 15) << 2;
        float4 v = ((const float4*)g)[f];
        float4 wv;
        wv.x = (v.x - ((r == c4 + 0) ? 4.7f : 0.0f)) * (1.0f / 3.8f);
        wv.y = (v.y - ((r == c4 + 1) ? 4.7f : 0.0f)) * (1.0f / 3.8f);
        wv.z = (v.z - ((r == c4 + 2) ? 4.7f : 0.0f)) * (1.0f / 3.8f);
        wv.w = (v.w - ((r == c4 + 3) ? 4.7f : 0.0f)) * (1.0f / 3.8f);
        uint2v sh, sl;
        sh[0] = pk2rn(wv.x, wv.y);
        sh[1] = pk2rn(wv.z, wv.w);
        sl[0] = rem_pk(sh[0], wv.x, wv.y, mone);
        sl[1] = rem_pk(sh[1], wv.z, wv.w, mone);
        *(uint2v*)(w16h + r * 68 + c4) = sh;
        *(uint2v*)(w16l + r * 68 + c4) = sl;
    }
    __syncthreads();  // single-wave block: just orders LDS

    // ---- P1 frags: hi and lo straight from the LDS planes (row reads).
    hfrag wfh[2][4], wfl[2][4];
#pragma unroll
    for (int t = 0; t < 2; ++t)
#pragma unroll
        for (int kb = 0; kb < 4; ++kb) {
            int row = (t << 5) + ln, q0 = (kb << 4) + (h << 3);
            uint2v a0 = *(const uint2v*)(w16h + row * 68 + q0);
            uint2v a1 = *(const uint2v*)(w16h + row * 68 + q0 + 4);
            uint2v b0 = *(const uint2v*)(w16l + row * 68 + q0);
            uint2v b1 = *(const uint2v*)(w16l + row * 68 + q0 + 4);
            uint4v uh, ul;
            uh[0] = a0[0]; uh[1] = a0[1]; uh[2] = a1[0]; uh[3] = a1[1];
            ul[0] = b0[0]; ul[1] = b0[1]; ul[2] = b1[0]; ul[3] = b1[1];
            wfh[t][kb] = __builtin_bit_cast(hfrag, uh);
            wfl[t][kb] = __builtin_bit_cast(hfrag, ul);
        }

    // ---- P1: W2 = w*w (hh + hl + lh -> near-exact, exactly symmetric).
    facc c[2][2];
#pragma unroll
    for (int ti = 0; ti < 2; ++ti)
#pragma unroll
        for (int tj = 0; tj < 2; ++tj) c[ti][tj] = (facc)0.0f;
    __builtin_amdgcn_s_setprio(1);
#pragma unroll
    for (int kb = 0; kb < 4; ++kb)
#pragma unroll
        for (int ti = 0; ti < 2; ++ti) {
            hfrag ah = wfh[ti][kb], al = wfl[ti][kb];
#pragma unroll
            for (int tj = 0; tj < 2; ++tj) {
                c[ti][tj] = MFMA(ah, wfh[tj][kb], c[ti][tj]);
                c[ti][tj] = MFMA(ah, wfl[tj][kb], c[ti][tj]);
                c[ti][tj] = MFMA(al, wfh[tj][kb], c[ti][tj]);
            }
        }
    __builtin_amdgcn_s_setprio(0);

    // ---- W2 B-frags: single RNE f16, persistent (32 VGPR).
    hfrag W2f[2][4];
#pragma unroll
    for (int kb = 0; kb < 4; ++kb)
#pragma unroll
        for (int tj = 0; tj < 2; ++tj)
            W2f[tj][kb] = round_frag(c[kb >> 1][tj], kb & 1);

    // ---- T = q5, then Horner s=4..0 fully in place.
    facc T[2][2];
    qs_fill(T, w16h, dvp, ln, h, Bc[10], Bc[11]);
    horner_step_ip(T, W2f, w16h, dvp, ln, h, Bc[8], Bc[9]);  // s=4
    horner_step_ip(T, W2f, w16h, dvp, ln, h, Bc[6], Bc[7]);  // s=3
    horner_step_ip(T, W2f, w16h, dvp, ln, h, Bc[4], Bc[5]);  // s=2
    horner_step_ip(T, W2f, w16h, dvp, ln, h, Bc[2], Bc[3]);  // s=1
    horner_step_ip(T, W2f, w16h, dvp, ln, h, Bc[0], Bc[1]);  // s=0

    // ---- out = T: C-layout straight to global (two 128B segments/instr)
#pragma unroll
    for (int ti = 0; ti < 2; ++ti)
#pragma unroll
        for (int tj = 0; tj < 2; ++tj)
#pragma unroll
            for (int reg = 0; reg < 16; ++reg) {
                int row = (ti << 5) + (reg & 3) + ((reg >> 2) << 3) + (h << 2);
                go[(row << 6) + (tj << 5) + ln] = T[ti][tj][reg];
            }
}

extern "C" void kernel_launch(void* const* d_in, const int* in_sizes, int n_in,
                              void* d_out, int out_size, void* d_ws, size_t ws_size,
                              hipStream_t stream) {
    const float* in = (const float*)d_in[0];
    float* out = (float*)d_out;
    const int batch = in_sizes[0] >> 12;  // 8192 matrices of 64x64
    hipLaunchKernelGGL(logeig_mfma_kernel, dim3(batch), dim3(64), 0,
                       stream, in, out);
}